// Round 1
// baseline (301.481 us; speedup 1.0000x reference)
//
#include <hip/hip_runtime.h>

// GQA_22436909154699: softmax over a size-1 axis == 1.0, so the reference
// reduces to  out[bl, g*512+h*64+d] = (x @ Wkv + bkv)[bl, g*128+64+d].
// => one (16384 x 2048) @ (2048 x 256) GEMM (v-columns only) + broadcast x8.
// Memory-bound: ~270 MB HBM traffic -> ~43 us floor. f16 MFMA for compute.

#define EMBED 2048
#define NV 256           // number of v columns
#define BM 32            // M rows per block
#define BK 32            // K per iteration
#define KITERS (EMBED / BK)
#define LDS_STRIDE 40    // halfs per row (80 B: 16B-aligned, <=2-way banks)
#define VS 260           // fp32 V-tile row stride (16B-aligned, 2-way banks)

typedef _Float16 half8 __attribute__((ext_vector_type(8)));
typedef _Float16 half4v __attribute__((ext_vector_type(4)));
typedef float f32x4 __attribute__((ext_vector_type(4)));

// ---- pre-pass: Bt[n][k] (f16) = Wkv[k][vcol(n)], vcol(n)=(n>>6)*128+64+(n&63)
__global__ __launch_bounds__(256) void prep_b(const float* __restrict__ Wkv,
                                              _Float16* __restrict__ Bt) {
  __shared__ _Float16 T[256 * 72];  // stride 72 halfs = 144 B (16B-aligned rows)
  const int t = threadIdx.x;
  const int kb = blockIdx.x * 64;   // 32 blocks cover k = 0..2047
  const int vcol = ((t >> 6) * 128) + 64 + (t & 63);
  for (int i = 0; i < 64; ++i) {
    T[t * 72 + i] = (_Float16)Wkv[(size_t)(kb + i) * 512 + vcol];
  }
  __syncthreads();
  const half8* src = (const half8*)&T[t * 72];
  half8* dst = (half8*)&Bt[(size_t)t * EMBED + kb];
#pragma unroll
  for (int c = 0; c < 8; ++c) dst[c] = src[c];
}

// ---- main: V = x @ Bt^T + bias, broadcast-write
__global__ __launch_bounds__(256, 2) void gqa_main(
    const float* __restrict__ x, const _Float16* __restrict__ Bt,
    const float* __restrict__ bkv, float* __restrict__ out) {
  extern __shared__ char smem[];
  _Float16* As = (_Float16*)smem;                          // 32  x 40 halfs
  _Float16* Bs = (_Float16*)(smem + BM * LDS_STRIDE * 2);  // 256 x 40 halfs
  float* Vs = (float*)smem;                                // union: 32 x 260 fp32

  const int tid = threadIdx.x;
  const int wave = tid >> 6;
  const int lane = tid & 63;
  const int lm = lane & 15;   // row-within-16 of the fragment
  const int lq = lane >> 4;   // quad -> k-chunk / output row group
  const int r0 = blockIdx.x * BM;

  // staging addresses
  const int am = tid >> 3, ak = (tid & 7) * 4;            // A: 32 rows x 8 float4
  const float* ap = x + (size_t)(r0 + am) * EMBED + ak;
  const int bn = tid >> 2, bc = (tid & 3) * 8;            // B: 64 rows x 4 chunks (x4 row-groups)
  const _Float16* bp = Bt + (size_t)bn * EMBED + bc;
  _Float16* awr = As + am * LDS_STRIDE + ak;
  _Float16* bwr = Bs + bn * LDS_STRIDE + bc;

  // fragment read addresses (A: m = lm, k = lq*8+j ; B: n = lm, k = lq*8+j)
  const _Float16* ard0 = As + (0 * 16 + lm) * LDS_STRIDE + lq * 8;
  const _Float16* ard1 = As + (1 * 16 + lm) * LDS_STRIDE + lq * 8;
  const _Float16* brd = Bs + (wave * 64 + lm) * LDS_STRIDE + lq * 8;  // +ni*16 rows

  f32x4 acc[2][4] = {};

  // prefetch iter 0
  float4 aReg = *(const float4*)ap;
  half8 bReg0 = *(const half8*)(bp);
  half8 bReg1 = *(const half8*)(bp + 64 * EMBED);
  half8 bReg2 = *(const half8*)(bp + 128 * EMBED);
  half8 bReg3 = *(const half8*)(bp + 192 * EMBED);

  for (int kt = 0; kt < KITERS; ++kt) {
    // stage into LDS
    half4v ah = {(_Float16)aReg.x, (_Float16)aReg.y, (_Float16)aReg.z,
                 (_Float16)aReg.w};
    *(half4v*)awr = ah;
    *(half8*)(bwr + 0 * 64 * LDS_STRIDE) = bReg0;
    *(half8*)(bwr + 1 * 64 * LDS_STRIDE) = bReg1;
    *(half8*)(bwr + 2 * 64 * LDS_STRIDE) = bReg2;
    *(half8*)(bwr + 3 * 64 * LDS_STRIDE) = bReg3;
    __syncthreads();

    if (kt + 1 < KITERS) {  // prefetch next k-slab
      ap += BK;
      bp += BK;
      aReg = *(const float4*)ap;
      bReg0 = *(const half8*)(bp);
      bReg1 = *(const half8*)(bp + 64 * EMBED);
      bReg2 = *(const half8*)(bp + 128 * EMBED);
      bReg3 = *(const half8*)(bp + 192 * EMBED);
    }

    half8 a0 = *(const half8*)ard0;
    half8 a1 = *(const half8*)ard1;
#pragma unroll
    for (int ni = 0; ni < 4; ++ni) {
      half8 bf = *(const half8*)(brd + ni * 16 * LDS_STRIDE);
      acc[0][ni] = __builtin_amdgcn_mfma_f32_16x16x32_f16(a0, bf, acc[0][ni], 0, 0, 0);
      acc[1][ni] = __builtin_amdgcn_mfma_f32_16x16x32_f16(a1, bf, acc[1][ni], 0, 0, 0);
    }
    __syncthreads();  // also guards the LDS union below on the last iter
  }

  // bias + write V tile to LDS (C/D layout: col = lane&15, row = lq*4 + r)
#pragma unroll
  for (int ni = 0; ni < 4; ++ni) {
    const int ncol = wave * 64 + ni * 16 + lm;
    const float bias = bkv[((ncol >> 6) * 128) + 64 + (ncol & 63)];
#pragma unroll
    for (int mi = 0; mi < 2; ++mi) {
      f32x4 a = acc[mi][ni];
#pragma unroll
      for (int r = 0; r < 4; ++r) {
        Vs[(mi * 16 + lq * 4 + r) * VS + ncol] = a[r] + bias;
      }
    }
  }
  __syncthreads();

  // broadcast epilogue: out[r0+m][c] = V[m][(c>>9)*64 + (c&63)], coalesced float4
  float4* out4 = (float4*)out;
  const size_t obase = (size_t)r0 * 512;  // 512 float4 per output row
#pragma unroll 4
  for (int i = 0; i < 64; ++i) {
    const int f = i * 256 + tid;   // flat float4 index in the 32x2048 tile
    const int m = f >> 9;
    const int c4 = f & 511;
    const int g = c4 >> 7;
    const int d4 = c4 & 15;
    float4 v = *(const float4*)&Vs[m * VS + g * 64 + d4 * 4];
    out4[obase + (size_t)f] = v;
  }
}

extern "C" void kernel_launch(void* const* d_in, const int* in_sizes, int n_in,
                              void* d_out, int out_size, void* d_ws, size_t ws_size,
                              hipStream_t stream) {
  const float* x = (const float*)d_in[0];
  // d_in[1] = Wq, d_in[2] = bq : dead code (softmax over size-1 axis == 1)
  const float* Wkv = (const float*)d_in[3];
  const float* bkv = (const float*)d_in[4];
  float* out = (float*)d_out;
  _Float16* Bt = (_Float16*)d_ws;  // 256*2048 f16 = 1 MB scratch

  prep_b<<<32, 256, 0, stream>>>(Wkv, Bt);

  const int mblocks = (4 * 4096) / BM;  // 512
  const size_t lds_bytes = 32 * VS * 4; // 33280 (>= staging 23040)
  gqa_main<<<mblocks, 256, lds_bytes, stream>>>(x, Bt, bkv, out);
}